// Round 16
// baseline (400.766 us; speedup 1.0000x reference)
//
#include <hip/hip_runtime.h>
#include <hip/hip_bf16.h>

#define B_   32
#define D_   512
#define L_   49
#define E_   4
#define KD_  4
#define NS_  16
#define RK_  32
#define JOBS_ 64

typedef short s16x8 __attribute__((ext_vector_type(8)));
typedef float f32x4v __attribute__((ext_vector_type(4)));
union U4 { uint4 u; s16x8 s; unsigned short us[8]; };

// ---------- helpers ----------
__device__ __forceinline__ float bf2f(unsigned short u){
  union{unsigned int i; float f;} v; v.i = ((unsigned int)u)<<16; return v.f;
}
__device__ __forceinline__ float2 bfp(unsigned int u){
  union{unsigned int i; float f;} a, b; a.i = u<<16; b.i = u & 0xffff0000u;
  return make_float2(a.f, b.f);
}
__device__ __forceinline__ unsigned short f2bfu(float f){
  union{float f; unsigned int i;} u; u.f = f;
  unsigned int r = u.i + 0x7fffu + ((u.i >> 16) & 1u);
  return (unsigned short)(r >> 16);
}
__device__ __forceinline__ float silu_f(float x){ return x / (1.f + expf(-x)); }

// inline dtype detection: wave-ballot over x[0..63] viewed as bf16.
// bf16 N(0,1): exponent in [96,160) ~always; fp32-reinterpreted: ~62%.
__device__ __forceinline__ int detect_bf(const void* x){
  unsigned short u = ((const unsigned short*)x)[threadIdx.x & 63];
  int e = (u >> 7) & 0xff;
  unsigned long long m = __ballot(e >= 96 && e < 160);
  return __popcll(m) >= 56;
}

// dtype-agnostic loads: bf=1 -> bf16 (ushort), bf=0 -> float32
__device__ __forceinline__ float ldf(const void* p, size_t i, int bf){
  return bf ? bf2f(((const unsigned short*)p)[i]) : ((const float*)p)[i];
}
struct f8s{ float v[8]; };
__device__ __forceinline__ f8s ldf8(const void* p, size_t i, int bf){
  f8s r;
  if (bf){
    uint4 u = *(const uint4*)((const unsigned short*)p + i);
    float2 x = bfp(u.x), y = bfp(u.y), z = bfp(u.z), w = bfp(u.w);
    r.v[0]=x.x; r.v[1]=x.y; r.v[2]=y.x; r.v[3]=y.y;
    r.v[4]=z.x; r.v[5]=z.y; r.v[6]=w.x; r.v[7]=w.y;
  } else {
    const float4* q = (const float4*)((const float*)p + i);
    float4 a = q[0], b = q[1];
    r.v[0]=a.x; r.v[1]=a.y; r.v[2]=a.z; r.v[3]=a.w;
    r.v[4]=b.x; r.v[5]=b.y; r.v[6]=b.z; r.v[7]=b.w;
  }
  return r;
}
// load 8 elems as bf16 frag (bf16: direct; fp32: convert)
__device__ __forceinline__ U4 ldbf8(const void* p, size_t i, int bf){
  U4 r;
  if (bf){
    r.u = *(const uint4*)((const unsigned short*)p + i);
  } else {
    const float* q = (const float*)p + i;
    float4 a = *(const float4*)q, b = *(const float4*)(q+4);
    r.u.x = (unsigned)f2bfu(a.x) | ((unsigned)f2bfu(a.y) << 16);
    r.u.y = (unsigned)f2bfu(a.z) | ((unsigned)f2bfu(a.w) << 16);
    r.u.z = (unsigned)f2bfu(b.x) | ((unsigned)f2bfu(b.y) << 16);
    r.u.w = (unsigned)f2bfu(b.z) | ((unsigned)f2bfu(b.w) << 16);
  }
  return r;
}
// split 8 fp32 into hi (truncated bf16) + lo (rounded residual bf16)
__device__ __forceinline__ void split8(const float av[8], U4& hi, U4& lo){
  #pragma unroll
  for (int j = 0; j < 8; j++){
    union{float f; unsigned int i;} u; u.f = av[j];
    unsigned short h = (unsigned short)(u.i >> 16);   // trunc — residual goes to lo
    hi.us[j] = h;
    lo.us[j] = f2bfu(av[j] - bf2f(h));
  }
}

// direction index map: xs[k,d,l] = xc[d, dirmap(k,l)]; all four maps are involutions.
__device__ __forceinline__ int dirmap(int k, int l){
  if (k == 0) return l;
  if (k == 1) return 48 - l;
  if (k == 2) return (l % 7) * 7 + l / 7;
  int l2 = 48 - l; return (l2 % 7) * 7 + l2 / 7;
}

// ---------- gating decision from precomputed logits (wave-uniform, deterministic) ----------
// Returns the two selected experts + capacity-scaled gate values for batch b.
__device__ __forceinline__ void gatecalc(const float* __restrict__ logits, int b,
                                         int* e1o, float* v1o, int* e2o, float* v2o){
  float den[4] = {1e-6f, 1e-6f, 1e-6f, 1e-6f};
  float rj[4] = {0.f,0.f,0.f,0.f}; int selj = 3;
  for (int bb = 0; bb < B_; bb++){
    float l0=logits[bb*4+0], l1=logits[bb*4+1], l2=logits[bb*4+2], l3=logits[bb*4+3];
    float m = fmaxf(fmaxf(l0,l1), fmaxf(l2,l3));
    float e0=expf(l0-m), e1=expf(l1-m), e2=expf(l2-m), e3=expf(l3-m);
    float s = e0+e1+e2+e3;
    float r[4] = {e0/s, e1/s, e2/s, e3/s};
    int i1 = 0; float v1 = r[0];
    for (int e = 1; e < 4; e++) if (r[e] > v1){ v1 = r[e]; i1 = e; }
    int i2 = -1; float v2 = -1.f;
    for (int e = 0; e < 4; e++){ if (e == i1) continue; if (r[e] > v2){ v2 = r[e]; i2 = e; } }
    if (i1 < 0 || i1 > 3) i1 = 0;
    if (i2 < 0 || i2 > 3) i2 = (i1 + 1) & 3;
    den[i1] += r[i1]; den[i2] += r[i2];
    if (bb == b){
      rj[0]=r[0]; rj[1]=r[1]; rj[2]=r[2]; rj[3]=r[3];
      selj = (1<<i1) | (1<<i2);
    }
  }
  float gs[4];
  #pragma unroll
  for (int e = 0; e < 4; e++)
    gs[e] = ((selj>>e)&1) ? rj[e]*40.f/den[e] : 0.f;   // capacity = int(1.25*32) = 40
  int i1 = 0; float v1 = gs[0];
  for (int e = 1; e < 4; e++) if (gs[e] > v1){ v1 = gs[e]; i1 = e; }
  int i2 = -1; float v2 = -1e30f;
  for (int e = 0; e < 4; e++){ if (e == i1) continue; if (gs[e] > v2){ v2 = gs[e]; i2 = e; } }
  if (i1 < 0 || i1 > 3) i1 = 0;
  if (i2 < 0 || i2 > 3) i2 = (i1 + 1) & 3;
  *e1o = i1; *v1o = v1; *e2o = i2; *v2o = v2;
}
// expert for a job slot
__device__ __forceinline__ int gate_e(const float* logits, int job){
  int e1, e2; float v1, v2;
  gatecalc(logits, job >> 1, &e1, &v1, &e2, &v2);
  return (job & 1) ? e2 : e1;
}
// aux loss (finmix block 0 only)
__device__ __forceinline__ float gateaux(const float* __restrict__ logits){
  float imp[4] = {0,0,0,0}, ld[4] = {0,0,0,0};
  for (int bb = 0; bb < B_; bb++){
    float l0=logits[bb*4+0], l1=logits[bb*4+1], l2=logits[bb*4+2], l3=logits[bb*4+3];
    float m = fmaxf(fmaxf(l0,l1), fmaxf(l2,l3));
    float e0=expf(l0-m), e1=expf(l1-m), e2=expf(l2-m), e3=expf(l3-m);
    float s = e0+e1+e2+e3;
    float r[4] = {e0/s, e1/s, e2/s, e3/s};
    int i1 = 0; float v1 = r[0];
    for (int e = 1; e < 4; e++) if (r[e] > v1){ v1 = r[e]; i1 = e; }
    int i2 = -1; float v2 = -1.f;
    for (int e = 0; e < 4; e++){ if (e == i1) continue; if (r[e] > v2){ v2 = r[e]; i2 = e; } }
    if (i1 < 0 || i1 > 3) i1 = 0;
    if (i2 < 0 || i2 > 3) i2 = (i1 + 1) & 3;
    #pragma unroll
    for (int e = 0; e < 4; e++) imp[e] += r[e];
    ld[i1] += 1.f; ld[i2] += 1.f;
  }
  float a = 0.f;
  #pragma unroll
  for (int e = 0; e < 4; e++){
    float df = ld[e]*(1.f/B_) - imp[e]*(1.f/B_);
    a += df*df;
  }
  return 0.01f * 0.25f * a;
}

// ---------- 1. k_prep: wtrans (blocks 0..511) + bgate logits (blocks 512..543) ----------
__global__ __launch_bounds__(256) void k_prep(const void* __restrict__ x,
                                              const void* __restrict__ w,
                                              const void* __restrict__ wg,
                                              const void* __restrict__ bg,
                                              unsigned short* __restrict__ wt,
                                              float* __restrict__ logits){
  __shared__ unsigned short tile[64][72];     // wtrans tile (also covers bgate's tiny red)
  __shared__ float red[4][4];
  int bf = detect_bf(x);
  int blk = blockIdx.x;
  int t = threadIdx.x;
  if (blk < 512){
    int e = blk >> 7, cb = (blk >> 3) & 15, db = blk & 7;
    #pragma unroll
    for (int r = 0; r < 4; r++){
      int d  = r*16 + (t>>4);
      int c0 = (t&15)*4;
      size_t g = ((size_t)e*512 + db*64 + d)*1024 + cb*64 + c0;
      if (bf){
        uint2 u = *(const uint2*)((const unsigned short*)w + g);
        tile[c0+0][d] = (unsigned short)(u.x & 0xffffu);
        tile[c0+1][d] = (unsigned short)(u.x >> 16);
        tile[c0+2][d] = (unsigned short)(u.y & 0xffffu);
        tile[c0+3][d] = (unsigned short)(u.y >> 16);
      } else {
        float4 v = *(const float4*)((const float*)w + g);
        tile[c0+0][d] = f2bfu(v.x);
        tile[c0+1][d] = f2bfu(v.y);
        tile[c0+2][d] = f2bfu(v.z);
        tile[c0+3][d] = f2bfu(v.w);
      }
    }
    __syncthreads();
    #pragma unroll
    for (int r = 0; r < 2; r++){
      int o = r*256 + t;
      int c = o >> 3, d0 = (o & 7)*8;
      uint4 v = *(const uint4*)&tile[c][d0];
      *(uint4*)(wt + ((size_t)e*1024 + cb*64 + c)*512 + db*64 + d0) = v;
    }
  } else {
    int b = blk - 512;
    int wave = t >> 6, lane = t & 63;
    float p[4] = {0.f, 0.f, 0.f, 0.f};
    #pragma unroll
    for (int rep = 0; rep < 2; rep++){
      int d = t + rep*256;
      float s = 0.f;
      for (int l = 0; l < L_; l++) s += ldf(x, ((size_t)(b*L_ + l))*D_ + d, bf);
      float xfd = s * (1.f/49.f);
      #pragma unroll
      for (int e = 0; e < 4; e++) p[e] = fmaf(xfd, ldf(wg, (size_t)d*E_ + e, bf), p[e]);
    }
    #pragma unroll
    for (int off = 32; off > 0; off >>= 1){
      #pragma unroll
      for (int e = 0; e < 4; e++) p[e] += __shfl_down(p[e], off, 64);
    }
    if (lane == 0){
      #pragma unroll
      for (int e = 0; e < 4; e++) red[wave][e] = p[e];
    }
    __syncthreads();
    if (t < 4)
      logits[b*4 + t] = red[0][t]+red[1][t]+red[2][t]+red[3][t] + ldf(bg, t, bf);
  }
}

// ---------- 3. in_proj via MFMA + FUSED conv, 64-col tiles (4 blocks/CU) ----------
__global__ __launch_bounds__(256) void k_inproj_mfma(const void* __restrict__ x,
                                                     const unsigned short* __restrict__ wt,
                                                     const void* __restrict__ bias,
                                                     const void* __restrict__ cw,
                                                     const void* __restrict__ cb,
                                                     const float* __restrict__ logits,
                                                     unsigned short* __restrict__ zbuf,
                                                     float* __restrict__ xc){
  __shared__ float xzt[49*68];                // [row][c-local 0..63], stride 68
  int bf = detect_bf(x);
  int job = blockIdx.x, nt = blockIdx.y;
  int b = job >> 1;
  int e = gate_e(logits, job);
  int t = threadIdx.x;
  int wave = t >> 6, lane = t & 63;
  int l16 = lane & 15, quad = lane >> 4;
  int arow = wave*16 + l16; if (arow > 48) arow = 48;   // pad rows duplicate row 48
  size_t abase = ((size_t)(b*L_ + arow))*D_;
  int ct = nt*64;
  size_t bbase = ((size_t)(e*1024 + ct + l16))*D_;      // + s*16*512 + k
  f32x4v acc[4] = {};
  for (int k0 = 0; k0 < 512; k0 += 32){
    int k = k0 + quad*8;
    U4 a = ldbf8(x, abase + k, bf);
    #pragma unroll
    for (int s = 0; s < 4; s++){
      U4 bb;
      bb.u = *(const uint4*)(wt + bbase + (size_t)s*16*D_ + k);
      acc[s] = __builtin_amdgcn_mfma_f32_16x16x32_bf16(a.s, bb.s, acc[s], 0, 0, 0);
    }
  }
  int rb = wave*16 + quad*4;
  if (nt >= 8){
    #pragma unroll
    for (int s = 0; s < 4; s++){
      int c = ct + s*16 + l16;
      float bv = ldf(bias, (size_t)e*1024 + c, bf);
      #pragma unroll
      for (int r = 0; r < 4; r++){
        int row = rb + r;
        if (row < L_)
          zbuf[(size_t)job*25088 + row*D_ + (c - 512)] = f2bfu(acc[s][r] + bv);
      }
    }
    return;
  }
  // xz half: stage to LDS, then conv
  #pragma unroll
  for (int s = 0; s < 4; s++){
    int cl = s*16 + l16;
    float bv = ldf(bias, (size_t)e*1024 + ct + cl, bf);
    #pragma unroll
    for (int r = 0; r < 4; r++){
      int row = rb + r;
      if (row < L_) xzt[row*68 + cl] = acc[s][r] + bv;
    }
  }
  __syncthreads();
  int c = t & 63, pg = t >> 6;                // 64 channels x 4 p-groups
  int dch = ct + c;
  float wv[9];
  #pragma unroll
  for (int j = 0; j < 9; j++) wv[j] = ldf(cw, ((size_t)(e*D_ + dch))*9 + j, bf);
  float cbv = ldf(cb, (size_t)e*D_ + dch, bf);
  for (int p = pg; p < L_; p += 4){
    int h = p / 7, w = p % 7;
    float a2 = cbv;
    #pragma unroll
    for (int dy = 0; dy < 3; dy++){
      int hh = h + dy - 1; if (hh < 0 || hh >= 7) continue;
      #pragma unroll
      for (int dx = 0; dx < 3; dx++){
        int ww = w + dx - 1; if (ww < 0 || ww >= 7) continue;
        a2 = fmaf(xzt[(hh*7+ww)*68 + c], wv[dy*3+dx], a2);
      }
    }
    xc[(size_t)job*25088 + (size_t)p*D_ + dch] = a2 * (1.f/(1.f+expf(-a2)));
  }
}

// ---------- 5. x_proj via MFMA v3: 16-row quarters, 4 blocks/CU ----------
__global__ __launch_bounds__(256) void k_xproj(const void* __restrict__ x,
                                               const void* __restrict__ xpw,
                                               const float* __restrict__ logits,
                                               const float* __restrict__ xc,
                                               float* __restrict__ xdbl){
  int bf = detect_bf(x);
  int kq = blockIdx.x, job = blockIdx.y;
  int k = kq & 3, q = kq >> 2;
  int t = threadIdx.x;
  int wave = t >> 6, lane = t & 63;
  int l16 = lane & 15, quad = lane >> 4;
  int e = gate_e(logits, job);
  int arow = q*16 + l16; if (arow > 48) arow = 48;      // q=3 pad rows dup row 48
  int m = dirmap(k, arow);
  const float* ap = xc + (size_t)job*25088 + (size_t)m*D_;
  size_t bbase = (((size_t)(e*KD_+k))*64 + wave*16 + l16)*D_;
  f32x4v acc = {};
  for (int k0 = 0; k0 < 512; k0 += 32){
    int kk = k0 + quad*8;
    const float* a8 = ap + kk;
    float4 f0 = *(const float4*)a8, f1 = *(const float4*)(a8+4);
    float av[8] = {f0.x,f0.y,f0.z,f0.w, f1.x,f1.y,f1.z,f1.w};
    U4 Ahi, Alo;
    split8(av, Ahi, Alo);
    U4 bb = ldbf8(xpw, bbase + kk, bf);
    acc = __builtin_amdgcn_mfma_f32_16x16x32_bf16(Ahi.s, bb.s, acc, 0, 0, 0);
    acc = __builtin_amdgcn_mfma_f32_16x16x32_bf16(Alo.s, bb.s, acc, 0, 0, 0);
  }
  float* outb = xdbl + ((size_t)(job*KD_+k))*3136;
  int rb = q*16 + quad*4;
  int c = wave*16 + l16;
  #pragma unroll
  for (int r = 0; r < 4; r++){
    int row = rb + r;
    if (row < L_) outb[row*64 + c] = acc[r];
  }
}

// ---------- 6. k_scan v4 (frozen config: 256 thr, 2-way state split) ----------
__global__ __launch_bounds__(256) void k_scan(const void* __restrict__ x,
                                              const void* __restrict__ dtw,
                                              const void* __restrict__ dtb_,
                                              const void* __restrict__ alog,
                                              const void* __restrict__ ds_,
                                              const float* __restrict__ logits,
                                              const float* __restrict__ xc,
                                              const float* __restrict__ xdbl,
                                              unsigned short* __restrict__ ybuf){
  int bf = detect_bf(x);
  int kz = blockIdx.x, job = blockIdx.y;
  int k = kz & 3, z = kz >> 2;                // z = d-quarter
  int t = threadIdx.x;
  int e = gate_e(logits, job);
  int ek = e*KD_ + k;
  __shared__ float xdl[3136];                 // [l][64] : dt_raw(32) | B(16) | C(16)
  __shared__ float dtl[49*132];               // dt[l][d_local 0..127], stride 132
  const float4* src4 = (const float4*)(xdbl + ((size_t)(job*KD_+k))*3136);
  for (int i = t; i < 784; i += 256) ((float4*)xdl)[i] = src4[i];
  __syncthreads();
  int wave = t >> 6, lane = t & 63;
  // ---- phase 1: dt GEMM (128 d's for this quarter) ----
  {
    int l16 = lane & 15, quad = lane >> 4;
    int arow = wave*16 + l16; if (arow > 48) arow = 48;
    const float* ap = &xdl[arow*64 + quad*8];
    float av[8];
    #pragma unroll
    for (int j = 0; j < 8; j++) av[j] = ap[j];
    U4 Ahi, Alo;
    split8(av, Ahi, Alo);
    f32x4v acc[8] = {};
    #pragma unroll
    for (int nt = 0; nt < 8; nt++){
      int d = z*128 + nt*16 + l16;
      U4 Bv = ldbf8(dtw, ((size_t)ek*D_ + d)*RK_ + quad*8, bf);
      acc[nt] = __builtin_amdgcn_mfma_f32_16x16x32_bf16(Ahi.s, Bv.s, acc[nt], 0, 0, 0);
      acc[nt] = __builtin_amdgcn_mfma_f32_16x16x32_bf16(Alo.s, Bv.s, acc[nt], 0, 0, 0);
    }
    #pragma unroll
    for (int nt = 0; nt < 8; nt++){
      int d = z*128 + nt*16 + l16;
      float bias = ldf(dtb_, (size_t)ek*D_ + d, bf);
      int dloc = nt*16 + l16;
      #pragma unroll
      for (int r = 0; r < 4; r++){
        int l = wave*16 + quad*4 + r;
        if (l < L_){
          float v = acc[nt][r] + bias;
          dtl[l*132 + dloc] = fmaxf(v, 0.f) + __logf(1.f + __expf(-fabsf(v)));
        }
      }
    }
  }
  // ---- phase 2 params: lane pair shares d, splits 16 states 8/8 ----
  int dl = wave*32 + (lane & 31);             // 0..127
  int ng = lane >> 5;                         // 0 or 1
  int d = z*128 + dl;
  float A2[8];
  {
    f8s ar = ldf8(alog, ((size_t)ek*D_ + d)*NS_ + ng*8, bf);
    #pragma unroll
    for (int j = 0; j < 8; j++) A2[j] = -expf(ar.v[j]) * 1.44269504f;
  }
  float Dsv = ldf(ds_, (size_t)ek*D_ + d, bf);
  __syncthreads();
  // ---- phase 2: scan, 7 chunks of 7 with x_t prefetch ----
  float h[8];
  #pragma unroll
  for (int n = 0; n < 8; n++) h[n] = 0.f;
  const float* xcb = xc + (size_t)job*25088;
  unsigned short* yb = ybuf + ((size_t)(job*KD_ + k))*25088;
  for (int c0 = 0; c0 < 49; c0 += 7){
    float xv[7];
    #pragma unroll
    for (int j = 0; j < 7; j++){
      int m = dirmap(k, c0 + j);
      xv[j] = xcb[(size_t)m*D_ + d];          // 7 independent loads -> MLP
    }
    #pragma unroll
    for (int j = 0; j < 7; j++){
      int l = c0 + j;
      float dt = dtl[l*132 + dl];
      float x_t = xv[j];
      float dtx = dt * x_t;
      const float4* Bp = (const float4*)&xdl[l*64 + 32 + ng*8];
      float4 B0 = Bp[0], B1 = Bp[1];
      const float4* Cp = (const float4*)&xdl[l*64 + 48 + ng*8];
      float4 C0 = Cp[0], C1 = Cp[1];
      float Bv[8] = {B0.x,B0.y,B0.z,B0.w, B1.x,B1.y,B1.z,B1.w};
      float Cv[8] = {C0.x,C0.y,C0.z,C0.w, C1.x,C1.y,C1.z,C1.w};
      float y = 0.f;
      #pragma unroll
      for (int n = 0; n < 8; n++){
        float en = exp2f(dt * A2[n]);
        h[n] = fmaf(h[n], en, dtx * Bv[n]);
        y = fmaf(h[n], Cv[n], y);
      }
      y += __shfl_down(y, 32);
      if (ng == 0) yb[(size_t)l*D_ + d] = f2bfu(fmaf(Dsv, x_t, y));
    }
  }
}

// ---------- 7a. k_final_a: per-(job, p mod 4) partial pools (256 blocks) ----------
__global__ __launch_bounds__(512) void k_final_a(const void* __restrict__ x,
                                                 const void* __restrict__ og,
                                                 const void* __restrict__ ob,
                                                 const float* __restrict__ logits,
                                                 const unsigned short* __restrict__ ybuf,
                                                 const unsigned short* __restrict__ zbuf,
                                                 float* __restrict__ partial){
  __shared__ float pool[8][512];
  int bf = detect_bf(x);
  int job = blockIdx.x, q = blockIdx.y, t = threadIdx.x;
  int wave = t >> 6, lane = t & 63;
  int e = gate_e(logits, job);
  int d0 = lane*8;
  const unsigned short* yb = ybuf + (size_t)job*KD_*25088;
  const unsigned short* zb = zbuf + (size_t)job*25088;
  float g[8], o[8];
  {
    f8s gg = ldf8(og, (size_t)e*D_ + d0, bf);
    f8s oo = ldf8(ob, (size_t)e*D_ + d0, bf);
    #pragma unroll
    for (int j = 0; j < 8; j++){ g[j] = gg.v[j]; o[j] = oo.v[j]; }
  }
  float acc[8] = {};
  for (int i = wave; i <= 12; i += 8){
    int p = q + 4*i;
    if (p >= L_) break;
    float v[8] = {};
    #pragma unroll
    for (int k = 0; k < KD_; k++){
      int l = dirmap(k, p);                   // involution
      U4 r; r.u = *(const uint4*)(yb + (size_t)k*25088 + (size_t)l*D_ + d0);
      #pragma unroll
      for (int j = 0; j < 8; j++) v[j] += bf2f(r.us[j]);
    }
    float s = 0.f, ss = 0.f;
    #pragma unroll
    for (int j = 0; j < 8; j++){ s += v[j]; ss += v[j]*v[j]; }
    #pragma unroll
    for (int off = 32; off > 0; off >>= 1){
      s  += __shfl_xor(s,  off, 64);
      ss += __shfl_xor(ss, off, 64);
    }
    float mu = s*(1.f/512.f);
    float var = ss*(1.f/512.f) - mu*mu;
    float rs = rsqrtf(var + 1e-5f);
    U4 zz; zz.u = *(const uint4*)(zb + (size_t)p*D_ + d0);
    #pragma unroll
    for (int j = 0; j < 8; j++){
      float zv = bf2f(zz.us[j]);
      acc[j] += ((v[j]-mu)*rs*g[j] + o[j]) * silu_f(zv);
    }
  }
  #pragma unroll
  for (int j = 0; j < 8; j++) pool[wave][d0+j] = acc[j];
  __syncthreads();
  float pd = pool[0][t]+pool[1][t]+pool[2][t]+pool[3][t]
           + pool[4][t]+pool[5][t]+pool[6][t]+pool[7][t];
  partial[((size_t)(job*4 + q))*512 + t] = pd;
}

// ---------- 7b. k_finmix: combine partials + final LN for both slots -> out ----------
__global__ __launch_bounds__(512) void k_finmix(const void* __restrict__ x,
                                                const void* __restrict__ ngg,
                                                const void* __restrict__ nbb,
                                                const float* __restrict__ logits,
                                                const float* __restrict__ partial,
                                                void* __restrict__ out){
  __shared__ float red[32];
  int bf = detect_bf(x);
  int b = blockIdx.x, t = threadIdx.x;
  int wave = t >> 6, lane = t & 63;
  int e0, e1; float g0, g1;
  gatecalc(logits, b, &e0, &g0, &e1, &g1);
  if (b == 0 && t == 0){
    float a = gateaux(logits);
    if (bf) ((unsigned short*)out)[16384] = f2bfu(a);
    else    ((float*)out)[16384] = a;
  }
  int j0 = 2*b, j1 = 2*b + 1;
  const float* p0 = partial + (size_t)j0*4*512;
  const float* p1 = partial + (size_t)j1*4*512;
  float pd0 = (p0[t] + p0[512+t] + p0[1024+t] + p0[1536+t]) * (1.f/49.f);
  float pd1 = (p1[t] + p1[512+t] + p1[1024+t] + p1[1536+t]) * (1.f/49.f);
  float s0 = pd0, ss0 = pd0*pd0, s1 = pd1, ss1 = pd1*pd1;
  #pragma unroll
  for (int off = 32; off > 0; off >>= 1){
    s0  += __shfl_down(s0,  off, 64);
    ss0 += __shfl_down(ss0, off, 64);
    s1  += __shfl_down(s1,  off, 64);
    ss1 += __shfl_down(ss1, off, 64);
  }
  if (lane == 0){
    red[wave] = s0; red[8+wave] = ss0; red[16+wave] = s1; red[24+wave] = ss1;
  }
  __syncthreads();
  s0 = red[0]+red[1]+red[2]+red[3]+red[4]+red[5]+red[6]+red[7];
  ss0 = red[8]+red[9]+red[10]+red[11]+red[12]+red[13]+red[14]+red[15];
  s1 = red[16]+red[17]+red[18]+red[19]+red[20]+red[21]+red[22]+red[23];
  ss1 = red[24]+red[25]+red[26]+red[27]+red[28]+red[29]+red[30]+red[31];
  float mu0 = s0*(1.f/512.f), var0 = ss0*(1.f/512.f) - mu0*mu0;
  float rs0 = rsqrtf(var0 + 1e-5f);
  float mu1 = s1*(1.f/512.f), var1 = ss1*(1.f/512.f) - mu1*mu1;
  float rs1 = rsqrtf(var1 + 1e-5f);
  float v0 = ((pd0-mu0)*rs0*ldf(ngg, (size_t)e0*D_+t, bf) + ldf(nbb, (size_t)e0*D_+t, bf)) * g0;
  float v1 = ((pd1-mu1)*rs1*ldf(ngg, (size_t)e1*D_+t, bf) + ldf(nbb, (size_t)e1*D_+t, bf)) * g1;
  float v = v0 + v1;
  if (bf) ((unsigned short*)out)[b*D_ + t] = f2bfu(v);
  else    ((float*)out)[b*D_ + t] = v;
}

extern "C" void kernel_launch(void* const* d_in, const int* in_sizes, int n_in,
                              void* d_out, int out_size, void* d_ws, size_t ws_size,
                              hipStream_t stream){
  const void* x    = d_in[0];
  const void* wg   = d_in[1];
  const void* bg   = d_in[2];
  const void* ipw  = d_in[3];
  const void* ipb  = d_in[4];
  const void* cw   = d_in[5];
  const void* cb   = d_in[6];
  const void* xpw  = d_in[7];
  const void* dtw  = d_in[8];
  const void* dtb  = d_in[9];
  const void* alog = d_in[10];
  const void* dss  = d_in[11];
  const void* ogg  = d_in[12];
  const void* obb  = d_in[13];
  const void* ngg  = d_in[14];
  const void* nbb  = d_in[15];
  float* wsf = (float*)d_ws;
  float* logits= wsf + 256;                                // 128
  float* xc    = wsf + 16640;                              // 1605632 (6.4MB)
  float* xdbl  = wsf + 1622272;                            // 802816 (3.2MB)
  unsigned short* zbuf = (unsigned short*)(wsf + 2425088); // 1605632 bf16 (3.2MB)
  // wtrans (4MB bf16) lives at the ybuf region start: read only by k_inproj_mfma,
  // which runs before k_scan writes ybuf. ybuf (12.8MB bf16) reuses it afterwards.
  unsigned short* ybuf   = (unsigned short*)(wsf + 3260672);
  unsigned short* wtrans = (unsigned short*)(wsf + 3260672);
  float* partial = wsf + 6471936;                          // 64*4*512 = 131072 (~0.5MB)

  k_prep  <<<544, 256, 0, stream>>>(x, ipw, wg, bg, wtrans, logits);
  k_inproj_mfma<<<dim3(64,16), 256, 0, stream>>>(x, wtrans, ipb, cw, cb, logits, zbuf, xc);
  k_xproj <<<dim3(16,64), 256, 0, stream>>>(x, xpw, logits, xc, xdbl);
  k_scan  <<<dim3(16,64), 256, 0, stream>>>(x, dtw, dtb, alog, dss, logits, xc, xdbl, ybuf);
  k_final_a<<<dim3(64,4), 512, 0, stream>>>(x, ogg, obb, logits, ybuf, zbuf, partial);
  k_finmix<<<32, 512, 0, stream>>>(x, ngg, nbb, logits, partial, d_out);
}

// Round 17
// 254.018 us; speedup vs baseline: 1.5777x; 1.5777x over previous
//
#include <hip/hip_runtime.h>
#include <hip/hip_bf16.h>

#define B_   32
#define D_   512
#define L_   49
#define E_   4
#define KD_  4
#define NS_  16
#define RK_  32
#define JOBS_ 64

typedef short s16x8 __attribute__((ext_vector_type(8)));
typedef float f32x4v __attribute__((ext_vector_type(4)));
union U4 { uint4 u; s16x8 s; unsigned short us[8]; };

// ---------- helpers ----------
__device__ __forceinline__ float bf2f(unsigned short u){
  union{unsigned int i; float f;} v; v.i = ((unsigned int)u)<<16; return v.f;
}
__device__ __forceinline__ float2 bfp(unsigned int u){
  union{unsigned int i; float f;} a, b; a.i = u<<16; b.i = u & 0xffff0000u;
  return make_float2(a.f, b.f);
}
__device__ __forceinline__ unsigned short f2bfu(float f){
  union{float f; unsigned int i;} u; u.f = f;
  unsigned int r = u.i + 0x7fffu + ((u.i >> 16) & 1u);
  return (unsigned short)(r >> 16);
}
__device__ __forceinline__ float silu_f(float x){ return x / (1.f + expf(-x)); }

// inline dtype detection: wave-ballot over x[0..63] viewed as bf16 (~5 instr).
__device__ __forceinline__ int detect_bf(const void* x){
  unsigned short u = ((const unsigned short*)x)[threadIdx.x & 63];
  int e = (u >> 7) & 0xff;
  unsigned long long m = __ballot(e >= 96 && e < 160);
  return __popcll(m) >= 56;
}

// dtype-agnostic loads: bf=1 -> bf16 (ushort), bf=0 -> float32
__device__ __forceinline__ float ldf(const void* p, size_t i, int bf){
  return bf ? bf2f(((const unsigned short*)p)[i]) : ((const float*)p)[i];
}
struct f8s{ float v[8]; };
__device__ __forceinline__ f8s ldf8(const void* p, size_t i, int bf){
  f8s r;
  if (bf){
    uint4 u = *(const uint4*)((const unsigned short*)p + i);
    float2 x = bfp(u.x), y = bfp(u.y), z = bfp(u.z), w = bfp(u.w);
    r.v[0]=x.x; r.v[1]=x.y; r.v[2]=y.x; r.v[3]=y.y;
    r.v[4]=z.x; r.v[5]=z.y; r.v[6]=w.x; r.v[7]=w.y;
  } else {
    const float4* q = (const float4*)((const float*)p + i);
    float4 a = q[0], b = q[1];
    r.v[0]=a.x; r.v[1]=a.y; r.v[2]=a.z; r.v[3]=a.w;
    r.v[4]=b.x; r.v[5]=b.y; r.v[6]=b.z; r.v[7]=b.w;
  }
  return r;
}
// load 8 elems as bf16 frag (bf16: direct; fp32: convert)
__device__ __forceinline__ U4 ldbf8(const void* p, size_t i, int bf){
  U4 r;
  if (bf){
    r.u = *(const uint4*)((const unsigned short*)p + i);
  } else {
    const float* q = (const float*)p + i;
    float4 a = *(const float4*)q, b = *(const float4*)(q+4);
    r.u.x = (unsigned)f2bfu(a.x) | ((unsigned)f2bfu(a.y) << 16);
    r.u.y = (unsigned)f2bfu(a.z) | ((unsigned)f2bfu(a.w) << 16);
    r.u.z = (unsigned)f2bfu(b.x) | ((unsigned)f2bfu(b.y) << 16);
    r.u.w = (unsigned)f2bfu(b.z) | ((unsigned)f2bfu(b.w) << 16);
  }
  return r;
}
// split 8 fp32 into hi (truncated bf16) + lo (rounded residual bf16)
__device__ __forceinline__ void split8(const float av[8], U4& hi, U4& lo){
  #pragma unroll
  for (int j = 0; j < 8; j++){
    union{float f; unsigned int i;} u; u.f = av[j];
    unsigned short h = (unsigned short)(u.i >> 16);   // trunc — residual goes to lo
    hi.us[j] = h;
    lo.us[j] = f2bfu(av[j] - bf2f(h));
  }
}

// direction index map: xs[k,d,l] = xc[d, dirmap(k,l)]; all four maps are involutions.
__device__ __forceinline__ int dirmap(int k, int l){
  if (k == 0) return l;
  if (k == 1) return 48 - l;
  if (k == 2) return (l % 7) * 7 + l / 7;
  int l2 = 48 - l; return (l2 % 7) * 7 + l2 / 7;
}

// ---------- 1. k_prep: wtrans (blocks 0..511) + bgate logits (blocks 512..543) ----------
__global__ __launch_bounds__(256) void k_prep(const void* __restrict__ x,
                                              const void* __restrict__ w,
                                              const void* __restrict__ wg,
                                              const void* __restrict__ bg,
                                              unsigned short* __restrict__ wt,
                                              float* __restrict__ logits){
  __shared__ unsigned short tile[64][72];
  __shared__ float red[4][4];
  int bf = detect_bf(x);
  int blk = blockIdx.x;
  int t = threadIdx.x;
  if (blk < 512){
    int e = blk >> 7, cb = (blk >> 3) & 15, db = blk & 7;
    #pragma unroll
    for (int r = 0; r < 4; r++){
      int d  = r*16 + (t>>4);
      int c0 = (t&15)*4;
      size_t g = ((size_t)e*512 + db*64 + d)*1024 + cb*64 + c0;
      if (bf){
        uint2 u = *(const uint2*)((const unsigned short*)w + g);
        tile[c0+0][d] = (unsigned short)(u.x & 0xffffu);
        tile[c0+1][d] = (unsigned short)(u.x >> 16);
        tile[c0+2][d] = (unsigned short)(u.y & 0xffffu);
        tile[c0+3][d] = (unsigned short)(u.y >> 16);
      } else {
        float4 v = *(const float4*)((const float*)w + g);
        tile[c0+0][d] = f2bfu(v.x);
        tile[c0+1][d] = f2bfu(v.y);
        tile[c0+2][d] = f2bfu(v.z);
        tile[c0+3][d] = f2bfu(v.w);
      }
    }
    __syncthreads();
    #pragma unroll
    for (int r = 0; r < 2; r++){
      int o = r*256 + t;
      int c = o >> 3, d0 = (o & 7)*8;
      uint4 v = *(const uint4*)&tile[c][d0];
      *(uint4*)(wt + ((size_t)e*1024 + cb*64 + c)*512 + db*64 + d0) = v;
    }
  } else {
    int b = blk - 512;
    int wave = t >> 6, lane = t & 63;
    float p[4] = {0.f, 0.f, 0.f, 0.f};
    #pragma unroll
    for (int rep = 0; rep < 2; rep++){
      int d = t + rep*256;
      float s = 0.f;
      for (int l = 0; l < L_; l++) s += ldf(x, ((size_t)(b*L_ + l))*D_ + d, bf);
      float xfd = s * (1.f/49.f);
      #pragma unroll
      for (int e = 0; e < 4; e++) p[e] = fmaf(xfd, ldf(wg, (size_t)d*E_ + e, bf), p[e]);
    }
    #pragma unroll
    for (int off = 32; off > 0; off >>= 1){
      #pragma unroll
      for (int e = 0; e < 4; e++) p[e] += __shfl_down(p[e], off, 64);
    }
    if (lane == 0){
      #pragma unroll
      for (int e = 0; e < 4; e++) red[wave][e] = p[e];
    }
    __syncthreads();
    if (t < 4)
      logits[b*4 + t] = red[0][t]+red[1][t]+red[2][t]+red[3][t] + ldf(bg, t, bf);
  }
}

// ---------- 2. k_gate2: softmax/top-k/aux from precomputed logits (1 block) ----------
__global__ __launch_bounds__(128) void k_gate2(const void* __restrict__ x,
                                               const float* __restrict__ logits,
                                               int* __restrict__ topi, float* __restrict__ topv,
                                               void* __restrict__ out){
  __shared__ float raw[B_*E_];
  __shared__ int   sel[B_];
  __shared__ float den[E_], auxp[E_];
  int bf = detect_bf(x);
  int t = threadIdx.x;
  if (t < B_){
    float l0=logits[t*4+0], l1=logits[t*4+1], l2=logits[t*4+2], l3=logits[t*4+3];
    float m = fmaxf(fmaxf(l0,l1), fmaxf(l2,l3));
    float e0=expf(l0-m), e1=expf(l1-m), e2=expf(l2-m), e3=expf(l3-m);
    float s = e0+e1+e2+e3;
    float r[4] = {e0/s, e1/s, e2/s, e3/s};
    int i1 = 0; float v1 = r[0];
    for (int e = 1; e < 4; e++) if (r[e] > v1){ v1 = r[e]; i1 = e; }
    int i2 = -1; float v2 = -1.f;
    for (int e = 0; e < 4; e++){ if (e == i1) continue; if (r[e] > v2){ v2 = r[e]; i2 = e; } }
    if (i1 < 0 || i1 > 3) i1 = 0;
    if (i2 < 0 || i2 > 3) i2 = (i1 + 1) & 3;
    sel[t] = (1<<i1) | (1<<i2);
    for (int e = 0; e < 4; e++) raw[t*4+e] = r[e];
  }
  __syncthreads();
  if (t < E_){
    float dn = 0.f, imp = 0.f, ld = 0.f;
    for (int b = 0; b < B_; b++){
      float r = raw[b*4+t];
      int bit = (sel[b] >> t) & 1;
      if (bit) dn += r;
      imp += r; ld += (float)bit;
    }
    den[t] = dn + 1e-6f;
    imp *= (1.f/B_); ld *= (1.f/B_);
    float df = ld - imp; auxp[t] = df*df;
  }
  __syncthreads();
  if (t == 0){
    float a = 0.01f * 0.25f * (auxp[0]+auxp[1]+auxp[2]+auxp[3]);
    if (bf) ((unsigned short*)out)[16384] = f2bfu(a);
    else    ((float*)out)[16384] = a;
  }
  if (t < B_){
    float gs[4];
    for (int e = 0; e < 4; e++){
      int bit = (sel[t] >> e) & 1;
      gs[e] = bit ? raw[t*4+e] * 40.f / den[e] : 0.f;   // capacity = int(1.25*32) = 40
    }
    int i1 = 0; float v1 = gs[0];
    for (int e = 1; e < 4; e++) if (gs[e] > v1){ v1 = gs[e]; i1 = e; }
    int i2 = -1; float v2 = -1e30f;
    for (int e = 0; e < 4; e++){ if (e == i1) continue; if (gs[e] > v2){ v2 = gs[e]; i2 = e; } }
    if (i1 < 0 || i1 > 3) i1 = 0;
    if (i2 < 0 || i2 > 3) i2 = (i1 + 1) & 3;
    topi[t*2+0] = i1; topv[t*2+0] = v1;
    topi[t*2+1] = i2; topv[t*2+1] = v2;
  }
}

// ---------- 3. in_proj via MFMA + FUSED conv, 64-col tiles (4 blocks/CU) ----------
__global__ __launch_bounds__(256) void k_inproj_mfma(const void* __restrict__ x,
                                                     const unsigned short* __restrict__ wt,
                                                     const void* __restrict__ bias,
                                                     const void* __restrict__ cw,
                                                     const void* __restrict__ cb,
                                                     const int* __restrict__ topi,
                                                     unsigned short* __restrict__ zbuf,
                                                     float* __restrict__ xc){
  __shared__ float xzt[49*68];                // [row][c-local 0..63], stride 68
  int bf = detect_bf(x);
  int job = blockIdx.x, nt = blockIdx.y;
  int b = job >> 1;
  int e = topi[job];
  int t = threadIdx.x;
  int wave = t >> 6, lane = t & 63;
  int l16 = lane & 15, quad = lane >> 4;
  int arow = wave*16 + l16; if (arow > 48) arow = 48;   // pad rows duplicate row 48
  size_t abase = ((size_t)(b*L_ + arow))*D_;
  int ct = nt*64;
  size_t bbase = ((size_t)(e*1024 + ct + l16))*D_;      // + s*16*512 + k
  f32x4v acc[4] = {};
  for (int k0 = 0; k0 < 512; k0 += 32){
    int k = k0 + quad*8;
    U4 a = ldbf8(x, abase + k, bf);
    #pragma unroll
    for (int s = 0; s < 4; s++){
      U4 bb;
      bb.u = *(const uint4*)(wt + bbase + (size_t)s*16*D_ + k);
      acc[s] = __builtin_amdgcn_mfma_f32_16x16x32_bf16(a.s, bb.s, acc[s], 0, 0, 0);
    }
  }
  int rb = wave*16 + quad*4;
  if (nt >= 8){
    #pragma unroll
    for (int s = 0; s < 4; s++){
      int c = ct + s*16 + l16;
      float bv = ldf(bias, (size_t)e*1024 + c, bf);
      #pragma unroll
      for (int r = 0; r < 4; r++){
        int row = rb + r;
        if (row < L_)
          zbuf[(size_t)job*25088 + row*D_ + (c - 512)] = f2bfu(acc[s][r] + bv);
      }
    }
    return;
  }
  // xz half: stage to LDS, then conv
  #pragma unroll
  for (int s = 0; s < 4; s++){
    int cl = s*16 + l16;
    float bv = ldf(bias, (size_t)e*1024 + ct + cl, bf);
    #pragma unroll
    for (int r = 0; r < 4; r++){
      int row = rb + r;
      if (row < L_) xzt[row*68 + cl] = acc[s][r] + bv;
    }
  }
  __syncthreads();
  int c = t & 63, pg = t >> 6;                // 64 channels x 4 p-groups
  int dch = ct + c;
  float wv[9];
  #pragma unroll
  for (int j = 0; j < 9; j++) wv[j] = ldf(cw, ((size_t)(e*D_ + dch))*9 + j, bf);
  float cbv = ldf(cb, (size_t)e*D_ + dch, bf);
  for (int p = pg; p < L_; p += 4){
    int h = p / 7, w = p % 7;
    float a2 = cbv;
    #pragma unroll
    for (int dy = 0; dy < 3; dy++){
      int hh = h + dy - 1; if (hh < 0 || hh >= 7) continue;
      #pragma unroll
      for (int dx = 0; dx < 3; dx++){
        int ww = w + dx - 1; if (ww < 0 || ww >= 7) continue;
        a2 = fmaf(xzt[(hh*7+ww)*68 + c], wv[dy*3+dx], a2);
      }
    }
    xc[(size_t)job*25088 + (size_t)p*D_ + dch] = a2 * (1.f/(1.f+expf(-a2)));
  }
}

// ---------- 5. x_proj via MFMA v3: 16-row quarters, 4 blocks/CU ----------
__global__ __launch_bounds__(256) void k_xproj(const void* __restrict__ x,
                                               const void* __restrict__ xpw,
                                               const int* __restrict__ topi,
                                               const float* __restrict__ xc,
                                               float* __restrict__ xdbl){
  int bf = detect_bf(x);
  int kq = blockIdx.x, job = blockIdx.y;
  int k = kq & 3, q = kq >> 2;
  int t = threadIdx.x;
  int wave = t >> 6, lane = t & 63;
  int l16 = lane & 15, quad = lane >> 4;
  int e = topi[job];
  int arow = q*16 + l16; if (arow > 48) arow = 48;      // q=3 pad rows dup row 48
  int m = dirmap(k, arow);
  const float* ap = xc + (size_t)job*25088 + (size_t)m*D_;
  size_t bbase = (((size_t)(e*KD_+k))*64 + wave*16 + l16)*D_;
  f32x4v acc = {};
  for (int k0 = 0; k0 < 512; k0 += 32){
    int kk = k0 + quad*8;
    const float* a8 = ap + kk;
    float4 f0 = *(const float4*)a8, f1 = *(const float4*)(a8+4);
    float av[8] = {f0.x,f0.y,f0.z,f0.w, f1.x,f1.y,f1.z,f1.w};
    U4 Ahi, Alo;
    split8(av, Ahi, Alo);
    U4 bb = ldbf8(xpw, bbase + kk, bf);
    acc = __builtin_amdgcn_mfma_f32_16x16x32_bf16(Ahi.s, bb.s, acc, 0, 0, 0);
    acc = __builtin_amdgcn_mfma_f32_16x16x32_bf16(Alo.s, bb.s, acc, 0, 0, 0);
  }
  float* outb = xdbl + ((size_t)(job*KD_+k))*3136;
  int rb = q*16 + quad*4;
  int c = wave*16 + l16;
  #pragma unroll
  for (int r = 0; r < 4; r++){
    int row = rb + r;
    if (row < L_) outb[row*64 + c] = acc[r];
  }
}

// ---------- 6. k_scan v4 (frozen config: 256 thr, 2-way state split) ----------
__global__ __launch_bounds__(256) void k_scan(const void* __restrict__ x,
                                              const void* __restrict__ dtw,
                                              const void* __restrict__ dtb_,
                                              const void* __restrict__ alog,
                                              const void* __restrict__ ds_,
                                              const int* __restrict__ topi,
                                              const float* __restrict__ xc,
                                              const float* __restrict__ xdbl,
                                              unsigned short* __restrict__ ybuf){
  int bf = detect_bf(x);
  int kz = blockIdx.x, job = blockIdx.y;
  int k = kz & 3, z = kz >> 2;                // z = d-quarter
  int t = threadIdx.x;
  int e = topi[job];
  int ek = e*KD_ + k;
  __shared__ float xdl[3136];                 // [l][64] : dt_raw(32) | B(16) | C(16)
  __shared__ float dtl[49*132];               // dt[l][d_local 0..127], stride 132
  const float4* src4 = (const float4*)(xdbl + ((size_t)(job*KD_+k))*3136);
  for (int i = t; i < 784; i += 256) ((float4*)xdl)[i] = src4[i];
  __syncthreads();
  int wave = t >> 6, lane = t & 63;
  // ---- phase 1: dt GEMM (128 d's for this quarter) ----
  {
    int l16 = lane & 15, quad = lane >> 4;
    int arow = wave*16 + l16; if (arow > 48) arow = 48;
    const float* ap = &xdl[arow*64 + quad*8];
    float av[8];
    #pragma unroll
    for (int j = 0; j < 8; j++) av[j] = ap[j];
    U4 Ahi, Alo;
    split8(av, Ahi, Alo);
    f32x4v acc[8] = {};
    #pragma unroll
    for (int nt = 0; nt < 8; nt++){
      int d = z*128 + nt*16 + l16;
      U4 Bv = ldbf8(dtw, ((size_t)ek*D_ + d)*RK_ + quad*8, bf);
      acc[nt] = __builtin_amdgcn_mfma_f32_16x16x32_bf16(Ahi.s, Bv.s, acc[nt], 0, 0, 0);
      acc[nt] = __builtin_amdgcn_mfma_f32_16x16x32_bf16(Alo.s, Bv.s, acc[nt], 0, 0, 0);
    }
    #pragma unroll
    for (int nt = 0; nt < 8; nt++){
      int d = z*128 + nt*16 + l16;
      float bias = ldf(dtb_, (size_t)ek*D_ + d, bf);
      int dloc = nt*16 + l16;
      #pragma unroll
      for (int r = 0; r < 4; r++){
        int l = wave*16 + quad*4 + r;
        if (l < L_){
          float v = acc[nt][r] + bias;
          dtl[l*132 + dloc] = fmaxf(v, 0.f) + __logf(1.f + __expf(-fabsf(v)));
        }
      }
    }
  }
  // ---- phase 2 params: lane pair shares d, splits 16 states 8/8 ----
  int dl = wave*32 + (lane & 31);             // 0..127
  int ng = lane >> 5;                         // 0 or 1
  int d = z*128 + dl;
  float A2[8];
  {
    f8s ar = ldf8(alog, ((size_t)ek*D_ + d)*NS_ + ng*8, bf);
    #pragma unroll
    for (int j = 0; j < 8; j++) A2[j] = -expf(ar.v[j]) * 1.44269504f;
  }
  float Dsv = ldf(ds_, (size_t)ek*D_ + d, bf);
  __syncthreads();
  // ---- phase 2: scan, 7 chunks of 7 with x_t prefetch ----
  float h[8];
  #pragma unroll
  for (int n = 0; n < 8; n++) h[n] = 0.f;
  const float* xcb = xc + (size_t)job*25088;
  unsigned short* yb = ybuf + ((size_t)(job*KD_ + k))*25088;
  for (int c0 = 0; c0 < 49; c0 += 7){
    float xv[7];
    #pragma unroll
    for (int j = 0; j < 7; j++){
      int m = dirmap(k, c0 + j);
      xv[j] = xcb[(size_t)m*D_ + d];          // 7 independent loads -> MLP
    }
    #pragma unroll
    for (int j = 0; j < 7; j++){
      int l = c0 + j;
      float dt = dtl[l*132 + dl];
      float x_t = xv[j];
      float dtx = dt * x_t;
      const float4* Bp = (const float4*)&xdl[l*64 + 32 + ng*8];
      float4 B0 = Bp[0], B1 = Bp[1];
      const float4* Cp = (const float4*)&xdl[l*64 + 48 + ng*8];
      float4 C0 = Cp[0], C1 = Cp[1];
      float Bv[8] = {B0.x,B0.y,B0.z,B0.w, B1.x,B1.y,B1.z,B1.w};
      float Cv[8] = {C0.x,C0.y,C0.z,C0.w, C1.x,C1.y,C1.z,C1.w};
      float y = 0.f;
      #pragma unroll
      for (int n = 0; n < 8; n++){
        float en = exp2f(dt * A2[n]);
        h[n] = fmaf(h[n], en, dtx * Bv[n]);
        y = fmaf(h[n], Cv[n], y);
      }
      y += __shfl_down(y, 32);
      if (ng == 0) yb[(size_t)l*D_ + d] = f2bfu(fmaf(Dsv, x_t, y));
    }
  }
}

// ---------- 7a. k_final_a: per-(job, p mod 4) partial pools (256 blocks) ----------
__global__ __launch_bounds__(512) void k_final_a(const void* __restrict__ x,
                                                 const void* __restrict__ og,
                                                 const void* __restrict__ ob,
                                                 const int* __restrict__ topi,
                                                 const unsigned short* __restrict__ ybuf,
                                                 const unsigned short* __restrict__ zbuf,
                                                 float* __restrict__ partial){
  __shared__ float pool[8][512];
  int bf = detect_bf(x);
  int job = blockIdx.x, q = blockIdx.y, t = threadIdx.x;
  int wave = t >> 6, lane = t & 63;
  int e = topi[job];
  int d0 = lane*8;
  const unsigned short* yb = ybuf + (size_t)job*KD_*25088;
  const unsigned short* zb = zbuf + (size_t)job*25088;
  float g[8], o[8];
  {
    f8s gg = ldf8(og, (size_t)e*D_ + d0, bf);
    f8s oo = ldf8(ob, (size_t)e*D_ + d0, bf);
    #pragma unroll
    for (int j = 0; j < 8; j++){ g[j] = gg.v[j]; o[j] = oo.v[j]; }
  }
  float acc[8] = {};
  for (int i = wave; i <= 12; i += 8){
    int p = q + 4*i;
    if (p >= L_) break;
    float v[8] = {};
    #pragma unroll
    for (int k = 0; k < KD_; k++){
      int l = dirmap(k, p);                   // involution
      U4 r; r.u = *(const uint4*)(yb + (size_t)k*25088 + (size_t)l*D_ + d0);
      #pragma unroll
      for (int j = 0; j < 8; j++) v[j] += bf2f(r.us[j]);
    }
    float s = 0.f, ss = 0.f;
    #pragma unroll
    for (int j = 0; j < 8; j++){ s += v[j]; ss += v[j]*v[j]; }
    #pragma unroll
    for (int off = 32; off > 0; off >>= 1){
      s  += __shfl_xor(s,  off, 64);
      ss += __shfl_xor(ss, off, 64);
    }
    float mu = s*(1.f/512.f);
    float var = ss*(1.f/512.f) - mu*mu;
    float rs = rsqrtf(var + 1e-5f);
    U4 zz; zz.u = *(const uint4*)(zb + (size_t)p*D_ + d0);
    #pragma unroll
    for (int j = 0; j < 8; j++){
      float zv = bf2f(zz.us[j]);
      acc[j] += ((v[j]-mu)*rs*g[j] + o[j]) * silu_f(zv);
    }
  }
  #pragma unroll
  for (int j = 0; j < 8; j++) pool[wave][d0+j] = acc[j];
  __syncthreads();
  float pd = pool[0][t]+pool[1][t]+pool[2][t]+pool[3][t]
           + pool[4][t]+pool[5][t]+pool[6][t]+pool[7][t];
  partial[((size_t)(job*4 + q))*512 + t] = pd;
}

// ---------- 7b. k_finmix: combine partials + final LN for both slots -> out ----------
__global__ __launch_bounds__(512) void k_finmix(const void* __restrict__ x,
                                                const void* __restrict__ ngg,
                                                const void* __restrict__ nbb,
                                                const int* __restrict__ topi,
                                                const float* __restrict__ topv,
                                                const float* __restrict__ partial,
                                                void* __restrict__ out){
  __shared__ float red[32];
  int bf = detect_bf(x);
  int b = blockIdx.x, t = threadIdx.x;
  int wave = t >> 6, lane = t & 63;
  int j0 = 2*b, j1 = 2*b + 1;
  int e0 = topi[j0], e1 = topi[j1];
  float g0 = topv[j0], g1 = topv[j1];
  const float* p0 = partial + (size_t)j0*4*512;
  const float* p1 = partial + (size_t)j1*4*512;
  float pd0 = (p0[t] + p0[512+t] + p0[1024+t] + p0[1536+t]) * (1.f/49.f);
  float pd1 = (p1[t] + p1[512+t] + p1[1024+t] + p1[1536+t]) * (1.f/49.f);
  float s0 = pd0, ss0 = pd0*pd0, s1 = pd1, ss1 = pd1*pd1;
  #pragma unroll
  for (int off = 32; off > 0; off >>= 1){
    s0  += __shfl_down(s0,  off, 64);
    ss0 += __shfl_down(ss0, off, 64);
    s1  += __shfl_down(s1,  off, 64);
    ss1 += __shfl_down(ss1, off, 64);
  }
  if (lane == 0){
    red[wave] = s0; red[8+wave] = ss0; red[16+wave] = s1; red[24+wave] = ss1;
  }
  __syncthreads();
  s0 = red[0]+red[1]+red[2]+red[3]+red[4]+red[5]+red[6]+red[7];
  ss0 = red[8]+red[9]+red[10]+red[11]+red[12]+red[13]+red[14]+red[15];
  s1 = red[16]+red[17]+red[18]+red[19]+red[20]+red[21]+red[22]+red[23];
  ss1 = red[24]+red[25]+red[26]+red[27]+red[28]+red[29]+red[30]+red[31];
  float mu0 = s0*(1.f/512.f), var0 = ss0*(1.f/512.f) - mu0*mu0;
  float rs0 = rsqrtf(var0 + 1e-5f);
  float mu1 = s1*(1.f/512.f), var1 = ss1*(1.f/512.f) - mu1*mu1;
  float rs1 = rsqrtf(var1 + 1e-5f);
  float v0 = ((pd0-mu0)*rs0*ldf(ngg, (size_t)e0*D_+t, bf) + ldf(nbb, (size_t)e0*D_+t, bf)) * g0;
  float v1 = ((pd1-mu1)*rs1*ldf(ngg, (size_t)e1*D_+t, bf) + ldf(nbb, (size_t)e1*D_+t, bf)) * g1;
  float v = v0 + v1;
  if (bf) ((unsigned short*)out)[b*D_ + t] = f2bfu(v);
  else    ((float*)out)[b*D_ + t] = v;
}

extern "C" void kernel_launch(void* const* d_in, const int* in_sizes, int n_in,
                              void* d_out, int out_size, void* d_ws, size_t ws_size,
                              hipStream_t stream){
  const void* x    = d_in[0];
  const void* wg   = d_in[1];
  const void* bg   = d_in[2];
  const void* ipw  = d_in[3];
  const void* ipb  = d_in[4];
  const void* cw   = d_in[5];
  const void* cb   = d_in[6];
  const void* xpw  = d_in[7];
  const void* dtw  = d_in[8];
  const void* dtb  = d_in[9];
  const void* alog = d_in[10];
  const void* dss  = d_in[11];
  const void* ogg  = d_in[12];
  const void* obb  = d_in[13];
  const void* ngg  = d_in[14];
  const void* nbb  = d_in[15];
  float* wsf = (float*)d_ws;
  int*   topi  = (int*)d_ws + 16;                          // [16..80)
  float* topv  = wsf + 96;                                 // [96..160)
  float* logits= wsf + 256;                                // 128
  float* xc    = wsf + 16640;                              // 1605632 (6.4MB)
  float* xdbl  = wsf + 1622272;                            // 802816 (3.2MB)
  unsigned short* zbuf = (unsigned short*)(wsf + 2425088); // 1605632 bf16 (3.2MB)
  // wtrans (4MB bf16) lives at the ybuf region start: read only by k_inproj_mfma,
  // which runs before k_scan writes ybuf. ybuf (12.8MB bf16) reuses it afterwards.
  unsigned short* ybuf   = (unsigned short*)(wsf + 3260672);
  unsigned short* wtrans = (unsigned short*)(wsf + 3260672);
  float* partial = wsf + 6471936;                          // 64*4*512 = 131072 (~0.5MB)

  k_prep  <<<544, 256, 0, stream>>>(x, ipw, wg, bg, wtrans, logits);
  k_gate2 <<<1, 128, 0, stream>>>(x, logits, topi, topv, d_out);
  k_inproj_mfma<<<dim3(64,16), 256, 0, stream>>>(x, wtrans, ipb, cw, cb, topi, zbuf, xc);
  k_xproj <<<dim3(16,64), 256, 0, stream>>>(x, xpw, topi, xc, xdbl);
  k_scan  <<<dim3(16,64), 256, 0, stream>>>(x, dtw, dtb, alog, dss, topi, xc, xdbl, ybuf);
  k_final_a<<<dim3(64,4), 512, 0, stream>>>(x, ogg, obb, topi, ybuf, zbuf, partial);
  k_finmix<<<32, 512, 0, stream>>>(x, ngg, nbb, topi, topv, partial, d_out);
}